// Round 10
// baseline (88.027 us; speedup 1.0000x reference)
//
#include <hip/hip_runtime.h>

typedef _Float16 f16x8 __attribute__((ext_vector_type(8)));
typedef float    f32x4 __attribute__((ext_vector_type(4)));

#define C_DIM 128
#define H_DIM 128
#define W_DIM 512
#define CH_STRIDE 65536      // H*W
#define V_STRIDE  8388608    // C*H*W
#define SJ 32                // j-strip width
#define NSTRIP 16            // 512 / 32
#define ROW_H 136            // halves per LDS row: 128 + 8 pad (272 B rows; dword stride 68 ≡ 4 mod 32 -> conflict-free b128 reads)

__global__ __launch_bounds__(512, 4) void costvol_kernel(
    const float* __restrict__ feat,
    const float* __restrict__ extri,
    const float* __restrict__ intri,
    const float* __restrict__ farp,
    float* __restrict__ out)
{
    __shared__ _Float16 Bs[2][SJ][ROW_H];   // 17408 B

    const int tid  = threadIdx.x;
    const int wave = tid >> 6;
    const int lane = tid & 63;
    const int l15  = lane & 15;
    const int l4   = lane >> 4;

    // XCD pair-swizzle: the two i-half blocks of one (b,h) land on the same XCD
    const int bid   = blockIdx.x;
    const int lb    = (bid & 7) * 128 + (bid >> 3);
    const int bh    = lb >> 1;
    const int ihalf = lb & 1;
    const int b  = bh >> 7;
    const int h  = bh & 127;
    const int rowbase = ihalf * 256 + wave * 32;   // wave owns 32 rows

    const float* lbase = feat + (size_t)(b * 2) * V_STRIDE + (size_t)h * W_DIM;
    const float* rbase = lbase + V_STRIDE;

    // staging mapping: jj = j within strip (32), c0 = 8 consecutive channels
    const int jj = tid & 31;
    const int c0 = (tid >> 5) * 8;

    float br[8];

#define ISSUE(s) do {                                                       \
    const float* bp_ = rbase + (size_t)((s) * SJ + jj);                     \
    _Pragma("unroll")                                                       \
    for (int d_ = 0; d_ < 8; ++d_)                                          \
        br[d_] = bp_[(size_t)(c0 + d_) * CH_STRIDE];                        \
} while (0)

#define STAGE(bf) do {                                                      \
    f16x8 w_;                                                               \
    _Pragma("unroll")                                                       \
    for (int d_ = 0; d_ < 8; ++d_) w_[d_] = (_Float16)br[d_];               \
    *(f16x8*)&Bs[bf][jj][c0] = w_;                                          \
} while (0)

    // ---- issue strip-0 loads (in flight across A-slab phase) ----
    ISSUE(0);
    __builtin_amdgcn_sched_barrier(0);

    // ---- A slab into registers: wave owns rows [rowbase, rowbase+32) ----
    // a-frag layout (16x16x32 f16 A-operand): row m = lane%16, k = (lane/16)*8 + e
    f16x8 a[2][4];   // [fi][ks]
    // 1/sqrt(128) * log2(e): epilogue uses exp2 (bare v_exp_f32, no per-elem mul)
    const float kScale = 0.08838834764831845f * 1.44269504088896340f;
    #pragma unroll
    for (int ks = 0; ks < 4; ++ks) {
        #pragma unroll
        for (int fi = 0; fi < 2; ++fi) {
            const float* p = lbase + (size_t)(ks * 32 + l4 * 8) * CH_STRIDE
                             + (size_t)(rowbase + fi * 16 + l15);
            f16x8 f;
            #pragma unroll
            for (int e = 0; e < 8; ++e)
                f[e] = (_Float16)(p[(size_t)e * CH_STRIDE] * kScale);
            a[fi][ks] = f;
        }
        __builtin_amdgcn_sched_barrier(0);   // cap in-flight load register pressure
    }

    // ---- write strip 0 into LDS buf 0 ----
    STAGE(0);
    __syncthreads();

    // per-lane row partials: slot = fi*4 + r  ->  row i = rowbase + fi*16 + l4*4 + r
    float Zp[8], Mp[8], Wp[8];
    #pragma unroll
    for (int s2 = 0; s2 < 8; ++s2) { Zp[s2] = 0.f; Mp[s2] = 0.f; Wp[s2] = 0.f; }

#define COMPUTE(bf, s) do {                                                  \
    f32x4 acc[2][2];                                                         \
    _Pragma("unroll")                                                        \
    for (int fi = 0; fi < 2; ++fi) {                                         \
        acc[fi][0] = (f32x4){0.f, 0.f, 0.f, 0.f};                            \
        acc[fi][1] = (f32x4){0.f, 0.f, 0.f, 0.f};                            \
    }                                                                        \
    __builtin_amdgcn_s_setprio(1);                                           \
    _Pragma("unroll")                                                        \
    for (int ks = 0; ks < 4; ++ks) {                                         \
        f16x8 b0 = *(const f16x8*)&Bs[bf][l15][ks * 32 + l4 * 8];            \
        f16x8 b1 = *(const f16x8*)&Bs[bf][16 + l15][ks * 32 + l4 * 8];       \
        _Pragma("unroll")                                                    \
        for (int fi = 0; fi < 2; ++fi) {                                     \
            acc[fi][0] = __builtin_amdgcn_mfma_f32_16x16x32_f16(a[fi][ks], b0, acc[fi][0], 0, 0, 0); \
            acc[fi][1] = __builtin_amdgcn_mfma_f32_16x16x32_f16(a[fi][ks], b1, acc[fi][1], 0, 0, 0); \
        }                                                                    \
    }                                                                        \
    __builtin_amdgcn_s_setprio(0);                                           \
    const int jbase_ = (s) * SJ;                                             \
    _Pragma("unroll")                                                        \
    for (int fi = 0; fi < 2; ++fi) {                                         \
        const int ti0 = rowbase + fi * 16;                                   \
        _Pragma("unroll")                                                    \
        for (int fj = 0; fj < 2; ++fj) {                                     \
            const int tj = jbase_ + fj * 16;                                 \
            const float jf = (float)(tj + l15);                              \
            if (tj + 15 <= ti0) {                /* fully inside tril */     \
                _Pragma("unroll")                                            \
                for (int r = 0; r < 4; ++r) {                                \
                    const int sl = fi * 4 + r;                               \
                    float e = exp2f(acc[fi][fj][r]);                         \
                    Zp[sl] += e;                                             \
                    Mp[sl] = fmaxf(Mp[sl], e);                               \
                    Wp[sl] += jf * e;                                        \
                }                                                            \
            } else if (tj > ti0 + 15) {          /* fully masked */          \
                _Pragma("unroll")                                            \
                for (int r = 0; r < 4; ++r) {                                \
                    float e = exp2f(acc[fi][fj][r]);                         \
                    Zp[fi * 4 + r] += e;                                     \
                }                                                            \
            } else {                             /* diagonal tile */         \
                _Pragma("unroll")                                            \
                for (int r = 0; r < 4; ++r) {                                \
                    const int sl = fi * 4 + r;                               \
                    float e = exp2f(acc[fi][fj][r]);                         \
                    Zp[sl] += e;                                             \
                    const int irow = ti0 + l4 * 4 + r;                       \
                    float em = ((tj + l15) <= irow) ? e : 0.f;               \
                    Mp[sl] = fmaxf(Mp[sl], em);                              \
                    Wp[sl] += jf * em;                                       \
                }                                                            \
            }                                                                \
        }                                                                    \
    }                                                                        \
} while (0)

    // ---- main loop: depth-1 register prefetch, LDS double-buffer ----
    int buf = 0;
    #pragma unroll 1
    for (int s = 0; s < NSTRIP; ++s) {
        if (s + 1 < NSTRIP) ISSUE(s + 1);
        __builtin_amdgcn_sched_barrier(0);
        COMPUTE(buf, s);
        if (s + 1 < NSTRIP) STAGE(buf ^ 1);
        __syncthreads();
        buf ^= 1;
    }

    // ---- cross-lane reduce: 16 lanes (same l4) hold one row's j-partials ----
    #pragma unroll
    for (int m = 1; m <= 8; m <<= 1) {
        #pragma unroll
        for (int sl = 0; sl < 8; ++sl) {
            Zp[sl] += __shfl_xor(Zp[sl], m, 64);
            Wp[sl] += __shfl_xor(Wp[sl], m, 64);
            Mp[sl] = fmaxf(Mp[sl], __shfl_xor(Mp[sl], m, 64));
        }
    }

    if (l15 == 0) {
        const float fx = intri[b * 18];                       // intri[b,0,0,0]
        const float dx = extri[b * 32 + 3]  - extri[b * 32 + 19];
        const float dy = extri[b * 32 + 7]  - extri[b * 32 + 23];
        const float dz = extri[b * 32 + 11] - extri[b * 32 + 27];
        const float bl = sqrtf(dx * dx + dy * dy + dz * dz);
        const float lfar = farp[b * 2];                       // far[b,0]
        const float kd = fx * bl / lfar;
        #pragma unroll
        for (int sl = 0; sl < 8; ++sl) {
            const int fi = sl >> 2, r = sl & 3;
            const int irow = rowbase + fi * 16 + l4 * 4 + r;
            const float Z = Zp[sl];
            const float conf = Mp[sl] / Z;
            const float corr = Wp[sl] / Z;
            float disp = fabsf(corr - (float)irow) * (1.0f / 512.0f);
            disp = fmaxf(disp, 0.1f);
            out[(size_t)(b * 2 + 0) * CH_STRIDE + h * W_DIM + irow] = kd / disp;
            out[(size_t)(b * 2 + 1) * CH_STRIDE + h * W_DIM + irow] = conf;
        }
    }
#undef ISSUE
#undef STAGE
#undef COMPUTE
}

extern "C" void kernel_launch(void* const* d_in, const int* in_sizes, int n_in,
                              void* d_out, int out_size, void* d_ws, size_t ws_size,
                              hipStream_t stream) {
    const float* feat  = (const float*)d_in[0];
    const float* extri = (const float*)d_in[1];
    const float* intri = (const float*)d_in[2];
    const float* farp  = (const float*)d_in[4];   // d_in[3] = near (unused)
    float* out = (float*)d_out;
    costvol_kernel<<<dim3(1024), dim3(512), 0, stream>>>(feat, extri, intri, farp, out);
}

// Round 11
// 76.578 us; speedup vs baseline: 1.1495x; 1.1495x over previous
//
#include <hip/hip_runtime.h>

typedef _Float16 f16x8 __attribute__((ext_vector_type(8)));
typedef float    f32x4 __attribute__((ext_vector_type(4)));

#define C_DIM 128
#define H_DIM 128
#define W_DIM 512
#define CH_STRIDE 65536      // H*W
#define V_STRIDE  8388608    // C*H*W
#define SJ 32                // j-strip width
#define NSTRIP 16            // 512 / 32
#define ROW_H 136            // halves per LDS row: 128 + 8 pad (272 B rows; dword stride 68 ≡ 4 mod 32 -> conflict-free b128 reads)

// raw v_exp_f32 (exp2): no OCML guard code, args bounded |x|<~15 so guards unneeded
#if defined(__has_builtin) && __has_builtin(__builtin_amdgcn_exp2f)
#define EXP2(x) __builtin_amdgcn_exp2f(x)
#else
__device__ __forceinline__ float __raw_exp2(float x) {
    float r;
    asm volatile("v_exp_f32 %0, %1" : "=v"(r) : "v"(x));
    return r;
}
#define EXP2(x) __raw_exp2(x)
#endif

__global__ __launch_bounds__(512, 4) void costvol_kernel(
    const float* __restrict__ feat,
    const float* __restrict__ extri,
    const float* __restrict__ intri,
    const float* __restrict__ farp,
    float* __restrict__ out)
{
    __shared__ _Float16 Bs[2][SJ][ROW_H];   // 17408 B

    const int tid  = threadIdx.x;
    const int wave = tid >> 6;
    const int lane = tid & 63;
    const int l15  = lane & 15;
    const int l4   = lane >> 4;

    // XCD pair-swizzle: the two i-half blocks of one (b,h) land on the same XCD
    const int bid   = blockIdx.x;
    const int lb    = (bid & 7) * 128 + (bid >> 3);
    const int bh    = lb >> 1;
    const int ihalf = lb & 1;
    const int b  = bh >> 7;
    const int h  = bh & 127;
    const int rowbase = ihalf * 256 + wave * 32;   // wave owns 32 rows

    const float* lbase = feat + (size_t)(b * 2) * V_STRIDE + (size_t)h * W_DIM;
    const float* rbase = lbase + V_STRIDE;

    // staging mapping: jj = j within strip (32), c0 = 8 consecutive channels
    const int jj = tid & 31;
    const int c0 = (tid >> 5) * 8;

    float br[8];

#define ISSUE(s) do {                                                       \
    const float* bp_ = rbase + (size_t)((s) * SJ + jj);                     \
    _Pragma("unroll")                                                       \
    for (int d_ = 0; d_ < 8; ++d_)                                          \
        br[d_] = bp_[(size_t)(c0 + d_) * CH_STRIDE];                        \
} while (0)

#define STAGE(bf) do {                                                      \
    f16x8 w_;                                                               \
    _Pragma("unroll")                                                       \
    for (int d_ = 0; d_ < 8; ++d_) w_[d_] = (_Float16)br[d_];               \
    *(f16x8*)&Bs[bf][jj][c0] = w_;                                          \
} while (0)

    // ---- issue strip-0 loads (in flight across A-slab phase) ----
    ISSUE(0);
    __builtin_amdgcn_sched_barrier(0);

    // ---- A slab into registers: wave owns rows [rowbase, rowbase+32) ----
    // a-frag layout (16x16x32 f16 A-operand): row m = lane%16, k = (lane/16)*8 + e
    f16x8 a[2][4];   // [fi][ks]
    // 1/sqrt(128) * log2(e): epilogue uses bare v_exp_f32 (exp2), no per-elem mul
    const float kScale = 0.08838834764831845f * 1.44269504088896340f;
    #pragma unroll
    for (int ks = 0; ks < 4; ++ks) {
        #pragma unroll
        for (int fi = 0; fi < 2; ++fi) {
            const float* p = lbase + (size_t)(ks * 32 + l4 * 8) * CH_STRIDE
                             + (size_t)(rowbase + fi * 16 + l15);
            f16x8 f;
            #pragma unroll
            for (int e = 0; e < 8; ++e)
                f[e] = (_Float16)(p[(size_t)e * CH_STRIDE] * kScale);
            a[fi][ks] = f;
        }
        __builtin_amdgcn_sched_barrier(0);   // cap in-flight load register pressure
    }

    // ---- write strip 0 into LDS buf 0 ----
    STAGE(0);
    __syncthreads();

    // per-lane row partials: slot = fi*4 + r  ->  row i = rowbase + fi*16 + l4*4 + r
    float Zp[8], Mp[8], Wp[8];
    #pragma unroll
    for (int s2 = 0; s2 < 8; ++s2) { Zp[s2] = 0.f; Mp[s2] = 0.f; Wp[s2] = 0.f; }

#define COMPUTE(bf, s) do {                                                  \
    f32x4 acc[2][2];                                                         \
    _Pragma("unroll")                                                        \
    for (int fi = 0; fi < 2; ++fi) {                                         \
        acc[fi][0] = (f32x4){0.f, 0.f, 0.f, 0.f};                            \
        acc[fi][1] = (f32x4){0.f, 0.f, 0.f, 0.f};                            \
    }                                                                        \
    __builtin_amdgcn_s_setprio(1);                                           \
    _Pragma("unroll")                                                        \
    for (int ks = 0; ks < 4; ++ks) {                                         \
        f16x8 b0 = *(const f16x8*)&Bs[bf][l15][ks * 32 + l4 * 8];            \
        f16x8 b1 = *(const f16x8*)&Bs[bf][16 + l15][ks * 32 + l4 * 8];       \
        _Pragma("unroll")                                                    \
        for (int fi = 0; fi < 2; ++fi) {                                     \
            acc[fi][0] = __builtin_amdgcn_mfma_f32_16x16x32_f16(a[fi][ks], b0, acc[fi][0], 0, 0, 0); \
            acc[fi][1] = __builtin_amdgcn_mfma_f32_16x16x32_f16(a[fi][ks], b1, acc[fi][1], 0, 0, 0); \
        }                                                                    \
    }                                                                        \
    __builtin_amdgcn_s_setprio(0);                                           \
    const int jbase_ = (s) * SJ;                                             \
    _Pragma("unroll")                                                        \
    for (int fi = 0; fi < 2; ++fi) {                                         \
        const int ti0 = rowbase + fi * 16;                                   \
        _Pragma("unroll")                                                    \
        for (int fj = 0; fj < 2; ++fj) {                                     \
            const int tj = jbase_ + fj * 16;                                 \
            const float jf = (float)(tj + l15);                              \
            if (tj + 15 <= ti0) {                /* fully inside tril */     \
                _Pragma("unroll")                                            \
                for (int r = 0; r < 4; ++r) {                                \
                    const int sl = fi * 4 + r;                               \
                    float e = EXP2(acc[fi][fj][r]);                          \
                    Zp[sl] += e;                                             \
                    Mp[sl] = fmaxf(Mp[sl], e);                               \
                    Wp[sl] += jf * e;                                        \
                }                                                            \
            } else if (tj > ti0 + 15) {          /* fully masked */          \
                _Pragma("unroll")                                            \
                for (int r = 0; r < 4; ++r) {                                \
                    float e = EXP2(acc[fi][fj][r]);                          \
                    Zp[fi * 4 + r] += e;                                     \
                }                                                            \
            } else {                             /* diagonal tile */         \
                _Pragma("unroll")                                            \
                for (int r = 0; r < 4; ++r) {                                \
                    const int sl = fi * 4 + r;                               \
                    float e = EXP2(acc[fi][fj][r]);                          \
                    Zp[sl] += e;                                             \
                    const int irow = ti0 + l4 * 4 + r;                       \
                    float em = ((tj + l15) <= irow) ? e : 0.f;               \
                    Mp[sl] = fmaxf(Mp[sl], em);                              \
                    Wp[sl] += jf * em;                                       \
                }                                                            \
            }                                                                \
        }                                                                    \
    }                                                                        \
} while (0)

    // ---- main loop: depth-1 register prefetch, LDS double-buffer ----
    int buf = 0;
    #pragma unroll 1
    for (int s = 0; s < NSTRIP; ++s) {
        if (s + 1 < NSTRIP) ISSUE(s + 1);
        __builtin_amdgcn_sched_barrier(0);
        COMPUTE(buf, s);
        if (s + 1 < NSTRIP) STAGE(buf ^ 1);
        __syncthreads();
        buf ^= 1;
    }

    // ---- cross-lane reduce: 16 lanes (same l4) hold one row's j-partials ----
    #pragma unroll
    for (int m = 1; m <= 8; m <<= 1) {
        #pragma unroll
        for (int sl = 0; sl < 8; ++sl) {
            Zp[sl] += __shfl_xor(Zp[sl], m, 64);
            Wp[sl] += __shfl_xor(Wp[sl], m, 64);
            Mp[sl] = fmaxf(Mp[sl], __shfl_xor(Mp[sl], m, 64));
        }
    }

    if (l15 == 0) {
        const float fx = intri[b * 18];                       // intri[b,0,0,0]
        const float dx = extri[b * 32 + 3]  - extri[b * 32 + 19];
        const float dy = extri[b * 32 + 7]  - extri[b * 32 + 23];
        const float dz = extri[b * 32 + 11] - extri[b * 32 + 27];
        const float bl = sqrtf(dx * dx + dy * dy + dz * dz);
        const float lfar = farp[b * 2];                       // far[b,0]
        const float kd = fx * bl / lfar;
        #pragma unroll
        for (int sl = 0; sl < 8; ++sl) {
            const int fi = sl >> 2, r = sl & 3;
            const int irow = rowbase + fi * 16 + l4 * 4 + r;
            const float Z = Zp[sl];
            const float conf = Mp[sl] / Z;
            const float corr = Wp[sl] / Z;
            float disp = fabsf(corr - (float)irow) * (1.0f / 512.0f);
            disp = fmaxf(disp, 0.1f);
            out[(size_t)(b * 2 + 0) * CH_STRIDE + h * W_DIM + irow] = kd / disp;
            out[(size_t)(b * 2 + 1) * CH_STRIDE + h * W_DIM + irow] = conf;
        }
    }
#undef ISSUE
#undef STAGE
#undef COMPUTE
}

extern "C" void kernel_launch(void* const* d_in, const int* in_sizes, int n_in,
                              void* d_out, int out_size, void* d_ws, size_t ws_size,
                              hipStream_t stream) {
    const float* feat  = (const float*)d_in[0];
    const float* extri = (const float*)d_in[1];
    const float* intri = (const float*)d_in[2];
    const float* farp  = (const float*)d_in[4];   // d_in[3] = near (unused)
    float* out = (float*)d_out;
    costvol_kernel<<<dim3(1024), dim3(512), 0, stream>>>(feat, extri, intri, farp, out);
}

// Round 12
// 74.825 us; speedup vs baseline: 1.1764x; 1.0234x over previous
//
#include <hip/hip_runtime.h>

typedef _Float16 f16x8 __attribute__((ext_vector_type(8)));
typedef float    f32x4 __attribute__((ext_vector_type(4)));

#define C_DIM 128
#define H_DIM 128
#define W_DIM 512
#define CH_STRIDE 65536      // H*W
#define V_STRIDE  8388608    // C*H*W
#define SJ 32                // j-strip width
#define NSTRIP 16            // 512 / 32
#define ROW_H 136            // halves per LDS row: 128 + 8 pad (272 B rows; dword stride 68 ≡ 4 mod 32 -> conflict-free b128 reads)
#define NBUF 8               // strip ring: staged at s-4, read at s, overwritten at s+4

// raw v_exp_f32 (exp2): no OCML guard code, args bounded |x|<~15 so guards unneeded
#if defined(__has_builtin) && __has_builtin(__builtin_amdgcn_exp2f)
#define EXP2(x) __builtin_amdgcn_exp2f(x)
#else
__device__ __forceinline__ float __raw_exp2(float x) {
    float r;
    asm volatile("v_exp_f32 %0, %1" : "=v"(r) : "v"(x));
    return r;
}
#define EXP2(x) __raw_exp2(x)
#endif

__global__ __launch_bounds__(512, 4) void costvol_kernel(
    const float* __restrict__ feat,
    const float* __restrict__ extri,
    const float* __restrict__ intri,
    const float* __restrict__ farp,
    float* __restrict__ out)
{
    __shared__ _Float16 Bs[NBUF][SJ][ROW_H];   // 69632 B -> 2 blocks/CU (139 KB <= 160 KB)

    const int tid  = threadIdx.x;
    const int wave = tid >> 6;
    const int lane = tid & 63;
    const int l15  = lane & 15;
    const int l4   = lane >> 4;

    // XCD pair-swizzle: the two i-half blocks of one (b,h) land on the same XCD
    const int bid   = blockIdx.x;
    const int lb    = (bid & 7) * 128 + (bid >> 3);
    const int bh    = lb >> 1;
    const int ihalf = lb & 1;
    const int b  = bh >> 7;
    const int h  = bh & 127;
    const int rowbase = ihalf * 256 + wave * 32;   // wave owns 32 rows

    const float* lbase = feat + (size_t)(b * 2) * V_STRIDE + (size_t)h * W_DIM;
    const float* rbase = lbase + V_STRIDE;

    // staging mapping: jj = j within strip (32), c0 = 8 consecutive channels
    const int jj = tid & 31;
    const int c0 = (tid >> 5) * 8;

    float br[8];

#define ISSUE(s) do {                                                       \
    const float* bp_ = rbase + (size_t)((s) * SJ + jj);                     \
    _Pragma("unroll")                                                       \
    for (int d_ = 0; d_ < 8; ++d_)                                          \
        br[d_] = bp_[(size_t)(c0 + d_) * CH_STRIDE];                        \
} while (0)

#define STAGE(bf) do {                                                      \
    f16x8 w_;                                                               \
    _Pragma("unroll")                                                       \
    for (int d_ = 0; d_ < 8; ++d_) w_[d_] = (_Float16)br[d_];               \
    *(f16x8*)&Bs[bf][jj][c0] = w_;                                          \
} while (0)

    // ---- prologue: stage strips 0-3 (A-slab loads overlap strip 0's latency) ----
    ISSUE(0);
    __builtin_amdgcn_sched_barrier(0);

    // ---- A slab into registers: wave owns rows [rowbase, rowbase+32) ----
    // a-frag layout (16x16x32 f16 A-operand): row m = lane%16, k = (lane/16)*8 + e
    f16x8 a[2][4];   // [fi][ks]
    // 1/sqrt(128) * log2(e): epilogue uses bare v_exp_f32 (exp2), no per-elem mul
    const float kScale = 0.08838834764831845f * 1.44269504088896340f;
    #pragma unroll
    for (int ks = 0; ks < 4; ++ks) {
        #pragma unroll
        for (int fi = 0; fi < 2; ++fi) {
            const float* p = lbase + (size_t)(ks * 32 + l4 * 8) * CH_STRIDE
                             + (size_t)(rowbase + fi * 16 + l15);
            f16x8 f;
            #pragma unroll
            for (int e = 0; e < 8; ++e)
                f[e] = (_Float16)(p[(size_t)e * CH_STRIDE] * kScale);
            a[fi][ks] = f;
        }
        __builtin_amdgcn_sched_barrier(0);   // cap in-flight load register pressure
    }

    STAGE(0);
    ISSUE(1); STAGE(1);
    ISSUE(2); STAGE(2);
    ISSUE(3); STAGE(3);
    __syncthreads();

    // per-lane row partials: slot = fi*4 + r  ->  row i = rowbase + fi*16 + l4*4 + r
    float Zp[8], Mp[8], Wp[8];
    #pragma unroll
    for (int s2 = 0; s2 < 8; ++s2) { Zp[s2] = 0.f; Mp[s2] = 0.f; Wp[s2] = 0.f; }

#define COMPUTE(bf, s) do {                                                  \
    f32x4 acc[2][2];                                                         \
    _Pragma("unroll")                                                        \
    for (int fi = 0; fi < 2; ++fi) {                                         \
        acc[fi][0] = (f32x4){0.f, 0.f, 0.f, 0.f};                            \
        acc[fi][1] = (f32x4){0.f, 0.f, 0.f, 0.f};                            \
    }                                                                        \
    __builtin_amdgcn_s_setprio(1);                                           \
    _Pragma("unroll")                                                        \
    for (int ks = 0; ks < 4; ++ks) {                                         \
        f16x8 b0 = *(const f16x8*)&Bs[bf][l15][ks * 32 + l4 * 8];            \
        f16x8 b1 = *(const f16x8*)&Bs[bf][16 + l15][ks * 32 + l4 * 8];       \
        _Pragma("unroll")                                                    \
        for (int fi = 0; fi < 2; ++fi) {                                     \
            acc[fi][0] = __builtin_amdgcn_mfma_f32_16x16x32_f16(a[fi][ks], b0, acc[fi][0], 0, 0, 0); \
            acc[fi][1] = __builtin_amdgcn_mfma_f32_16x16x32_f16(a[fi][ks], b1, acc[fi][1], 0, 0, 0); \
        }                                                                    \
    }                                                                        \
    __builtin_amdgcn_s_setprio(0);                                           \
    const int jbase_ = (s) * SJ;                                             \
    _Pragma("unroll")                                                        \
    for (int fi = 0; fi < 2; ++fi) {                                         \
        const int ti0 = rowbase + fi * 16;                                   \
        _Pragma("unroll")                                                    \
        for (int fj = 0; fj < 2; ++fj) {                                     \
            const int tj = jbase_ + fj * 16;                                 \
            const float jf = (float)(tj + l15);                              \
            if (tj + 15 <= ti0) {                /* fully inside tril */     \
                _Pragma("unroll")                                            \
                for (int r = 0; r < 4; ++r) {                                \
                    const int sl = fi * 4 + r;                               \
                    float e = EXP2(acc[fi][fj][r]);                          \
                    Zp[sl] += e;                                             \
                    Mp[sl] = fmaxf(Mp[sl], e);                               \
                    Wp[sl] += jf * e;                                        \
                }                                                            \
            } else if (tj > ti0 + 15) {          /* fully masked */          \
                _Pragma("unroll")                                            \
                for (int r = 0; r < 4; ++r) {                                \
                    float e = EXP2(acc[fi][fj][r]);                          \
                    Zp[fi * 4 + r] += e;                                     \
                }                                                            \
            } else {                             /* diagonal tile */         \
                _Pragma("unroll")                                            \
                for (int r = 0; r < 4; ++r) {                                \
                    const int sl = fi * 4 + r;                               \
                    float e = EXP2(acc[fi][fj][r]);                          \
                    Zp[sl] += e;                                             \
                    const int irow = ti0 + l4 * 4 + r;                       \
                    float em = ((tj + l15) <= irow) ? e : 0.f;               \
                    Mp[sl] = fmaxf(Mp[sl], em);                              \
                    Wp[sl] += jf * em;                                       \
                }                                                            \
            }                                                                \
        }                                                                    \
    }                                                                        \
} while (0)

    // ---- main loop: 8-buffer strip ring, barrier every 4 strips ----
    // strip s: staged at step s-4, read at step s, overwritten at step s+4;
    // read and overwrite are separated by the mega-phase barrier.
    #pragma unroll 4
    for (int s = 0; s < NSTRIP; ++s) {
        if (s + 4 < NSTRIP) ISSUE(s + 4);
        __builtin_amdgcn_sched_barrier(0);
        COMPUTE(s & 7, s);
        if (s + 4 < NSTRIP) STAGE((s + 4) & 7);
        if ((s & 3) == 3) __syncthreads();
    }

    // ---- cross-lane reduce: 16 lanes (same l4) hold one row's j-partials ----
    #pragma unroll
    for (int m = 1; m <= 8; m <<= 1) {
        #pragma unroll
        for (int sl = 0; sl < 8; ++sl) {
            Zp[sl] += __shfl_xor(Zp[sl], m, 64);
            Wp[sl] += __shfl_xor(Wp[sl], m, 64);
            Mp[sl] = fmaxf(Mp[sl], __shfl_xor(Mp[sl], m, 64));
        }
    }

    if (l15 == 0) {
        const float fx = intri[b * 18];                       // intri[b,0,0,0]
        const float dx = extri[b * 32 + 3]  - extri[b * 32 + 19];
        const float dy = extri[b * 32 + 7]  - extri[b * 32 + 23];
        const float dz = extri[b * 32 + 11] - extri[b * 32 + 27];
        const float bl = sqrtf(dx * dx + dy * dy + dz * dz);
        const float lfar = farp[b * 2];                       // far[b,0]
        const float kd = fx * bl / lfar;
        #pragma unroll
        for (int sl = 0; sl < 8; ++sl) {
            const int fi = sl >> 2, r = sl & 3;
            const int irow = rowbase + fi * 16 + l4 * 4 + r;
            const float Z = Zp[sl];
            const float conf = Mp[sl] / Z;
            const float corr = Wp[sl] / Z;
            float disp = fabsf(corr - (float)irow) * (1.0f / 512.0f);
            disp = fmaxf(disp, 0.1f);
            out[(size_t)(b * 2 + 0) * CH_STRIDE + h * W_DIM + irow] = kd / disp;
            out[(size_t)(b * 2 + 1) * CH_STRIDE + h * W_DIM + irow] = conf;
        }
    }
#undef ISSUE
#undef STAGE
#undef COMPUTE
}

extern "C" void kernel_launch(void* const* d_in, const int* in_sizes, int n_in,
                              void* d_out, int out_size, void* d_ws, size_t ws_size,
                              hipStream_t stream) {
    const float* feat  = (const float*)d_in[0];
    const float* extri = (const float*)d_in[1];
    const float* intri = (const float*)d_in[2];
    const float* farp  = (const float*)d_in[4];   // d_in[3] = near (unused)
    float* out = (float*)d_out;
    costvol_kernel<<<dim3(1024), dim3(512), 0, stream>>>(feat, extri, intri, farp, out);
}

// Round 13
// 73.302 us; speedup vs baseline: 1.2009x; 1.0208x over previous
//
#include <hip/hip_runtime.h>

typedef _Float16 f16x8 __attribute__((ext_vector_type(8)));
typedef _Float16 f16x2 __attribute__((ext_vector_type(2)));
typedef float    f32x4 __attribute__((ext_vector_type(4)));

#define C_DIM 128
#define H_DIM 128
#define W_DIM 512
#define CH_STRIDE 65536      // H*W
#define V_STRIDE  8388608    // C*H*W
#define SJ 32                // j-strip width
#define NSTRIP 16            // 512 / 32
#define ROW_H 136            // halves per LDS row: 128 + 8 pad (272 B rows; dword stride 68 ≡ 4 mod 32 -> conflict-free b128 reads, 4-way b32 writes)
#define NBUF 8               // strip ring: staged at s-4, read at s, overwritten at s+4

// raw v_exp_f32 (exp2): no OCML guard code, args bounded |x|<~15 so guards unneeded
#if defined(__has_builtin) && __has_builtin(__builtin_amdgcn_exp2f)
#define EXP2(x) __builtin_amdgcn_exp2f(x)
#else
__device__ __forceinline__ float __raw_exp2(float x) {
    float r;
    asm volatile("v_exp_f32 %0, %1" : "=v"(r) : "v"(x));
    return r;
}
#define EXP2(x) __raw_exp2(x)
#endif

__global__ __launch_bounds__(512, 4) void costvol_kernel(
    const float* __restrict__ feat,
    const float* __restrict__ extri,
    const float* __restrict__ intri,
    const float* __restrict__ farp,
    float* __restrict__ out)
{
    __shared__ _Float16 Bs[NBUF][SJ][ROW_H];   // 69632 B -> 2 blocks/CU

    const int tid  = threadIdx.x;
    const int wave = tid >> 6;
    const int lane = tid & 63;
    const int l15  = lane & 15;
    const int l4   = lane >> 4;

    // XCD pair-swizzle: the two i-half blocks of one (b,h) land on the same XCD
    const int bid   = blockIdx.x;
    const int lb    = (bid & 7) * 128 + (bid >> 3);
    const int bh    = lb >> 1;
    const int ihalf = lb & 1;
    const int b  = bh >> 7;
    const int h  = bh & 127;
    const int rowbase = ihalf * 256 + wave * 32;   // wave owns 32 rows

    const float* lbase = feat + (size_t)(b * 2) * V_STRIDE + (size_t)h * W_DIM;
    const float* rbase = lbase + V_STRIDE;

    // staging mapping: thread -> (j-quad jq, channel pair cc, cc+1)
    // global: lanes vary jq fastest -> 8 x 128B coalesced segments per load instr
    const int jq4 = (tid & 7) * 4;        // j-quad base within strip
    const int cc  = (tid >> 3) * 2;       // even channel 0..126

    f32x4 brv0, brv1;                     // float4 along j, channels cc and cc+1

#define ISSUE(s) do {                                                       \
    const float* bp_ = rbase + (size_t)cc * CH_STRIDE + (s) * SJ + jq4;     \
    brv0 = *(const f32x4*)bp_;                                              \
    brv1 = *(const f32x4*)(bp_ + CH_STRIDE);                                \
} while (0)

// transpose-in-LDS: 4 x b32 writes of packed (cc, cc+1) f16 pairs
#define STAGE(bf) do {                                                      \
    _Pragma("unroll")                                                       \
    for (int e_ = 0; e_ < 4; ++e_) {                                        \
        f16x2 w_;                                                           \
        w_[0] = (_Float16)brv0[e_];                                         \
        w_[1] = (_Float16)brv1[e_];                                         \
        *(f16x2*)&Bs[bf][jq4 + e_][cc] = w_;                                \
    }                                                                       \
} while (0)

    // ---- prologue: stage strips 0-3 (A-slab loads overlap strip 0's latency) ----
    ISSUE(0);
    __builtin_amdgcn_sched_barrier(0);

    // ---- A slab into registers: wave owns rows [rowbase, rowbase+32) ----
    // a-frag layout (16x16x32 f16 A-operand): row m = lane%16, k = (lane/16)*8 + e
    f16x8 a[2][4];   // [fi][ks]
    // 1/sqrt(128) * log2(e): epilogue uses bare v_exp_f32 (exp2), no per-elem mul
    const float kScale = 0.08838834764831845f * 1.44269504088896340f;
    #pragma unroll
    for (int ks = 0; ks < 4; ++ks) {
        #pragma unroll
        for (int fi = 0; fi < 2; ++fi) {
            const float* p = lbase + (size_t)(ks * 32 + l4 * 8) * CH_STRIDE
                             + (size_t)(rowbase + fi * 16 + l15);
            f16x8 f;
            #pragma unroll
            for (int e = 0; e < 8; ++e)
                f[e] = (_Float16)(p[(size_t)e * CH_STRIDE] * kScale);
            a[fi][ks] = f;
        }
        __builtin_amdgcn_sched_barrier(0);   // cap in-flight load register pressure
    }

    STAGE(0);
    ISSUE(1); STAGE(1);
    ISSUE(2); STAGE(2);
    ISSUE(3); STAGE(3);
    __syncthreads();

    // per-lane row partials: slot = fi*4 + r  ->  row i = rowbase + fi*16 + l4*4 + r
    float Zp[8], Mp[8], Wp[8];
    #pragma unroll
    for (int s2 = 0; s2 < 8; ++s2) { Zp[s2] = 0.f; Mp[s2] = 0.f; Wp[s2] = 0.f; }

#define COMPUTE(bf, s) do {                                                  \
    f32x4 acc[2][2];                                                         \
    _Pragma("unroll")                                                        \
    for (int fi = 0; fi < 2; ++fi) {                                         \
        acc[fi][0] = (f32x4){0.f, 0.f, 0.f, 0.f};                            \
        acc[fi][1] = (f32x4){0.f, 0.f, 0.f, 0.f};                            \
    }                                                                        \
    __builtin_amdgcn_s_setprio(1);                                           \
    _Pragma("unroll")                                                        \
    for (int ks = 0; ks < 4; ++ks) {                                         \
        f16x8 b0 = *(const f16x8*)&Bs[bf][l15][ks * 32 + l4 * 8];            \
        f16x8 b1 = *(const f16x8*)&Bs[bf][16 + l15][ks * 32 + l4 * 8];       \
        _Pragma("unroll")                                                    \
        for (int fi = 0; fi < 2; ++fi) {                                     \
            acc[fi][0] = __builtin_amdgcn_mfma_f32_16x16x32_f16(a[fi][ks], b0, acc[fi][0], 0, 0, 0); \
            acc[fi][1] = __builtin_amdgcn_mfma_f32_16x16x32_f16(a[fi][ks], b1, acc[fi][1], 0, 0, 0); \
        }                                                                    \
    }                                                                        \
    __builtin_amdgcn_s_setprio(0);                                           \
    const int jbase_ = (s) * SJ;                                             \
    _Pragma("unroll")                                                        \
    for (int fi = 0; fi < 2; ++fi) {                                         \
        const int ti0 = rowbase + fi * 16;                                   \
        _Pragma("unroll")                                                    \
        for (int fj = 0; fj < 2; ++fj) {                                     \
            const int tj = jbase_ + fj * 16;                                 \
            const float jf = (float)(tj + l15);                              \
            if (tj + 15 <= ti0) {                /* fully inside tril */     \
                _Pragma("unroll")                                            \
                for (int r = 0; r < 4; ++r) {                                \
                    const int sl = fi * 4 + r;                               \
                    float e = EXP2(acc[fi][fj][r]);                          \
                    Zp[sl] += e;                                             \
                    Mp[sl] = fmaxf(Mp[sl], e);                               \
                    Wp[sl] += jf * e;                                        \
                }                                                            \
            } else if (tj > ti0 + 15) {          /* fully masked */          \
                _Pragma("unroll")                                            \
                for (int r = 0; r < 4; ++r) {                                \
                    float e = EXP2(acc[fi][fj][r]);                          \
                    Zp[fi * 4 + r] += e;                                     \
                }                                                            \
            } else {                             /* diagonal tile */         \
                _Pragma("unroll")                                            \
                for (int r = 0; r < 4; ++r) {                                \
                    const int sl = fi * 4 + r;                               \
                    float e = EXP2(acc[fi][fj][r]);                          \
                    Zp[sl] += e;                                             \
                    const int irow = ti0 + l4 * 4 + r;                       \
                    float em = ((tj + l15) <= irow) ? e : 0.f;               \
                    Mp[sl] = fmaxf(Mp[sl], em);                              \
                    Wp[sl] += jf * em;                                       \
                }                                                            \
            }                                                                \
        }                                                                    \
    }                                                                        \
} while (0)

    // ---- main loop: 8-buffer strip ring, barrier every 4 strips ----
    #pragma unroll 4
    for (int s = 0; s < NSTRIP; ++s) {
        if (s + 4 < NSTRIP) ISSUE(s + 4);
        __builtin_amdgcn_sched_barrier(0);
        COMPUTE(s & 7, s);
        if (s + 4 < NSTRIP) STAGE((s + 4) & 7);
        if ((s & 3) == 3) __syncthreads();
    }

    // ---- cross-lane reduce: 16 lanes (same l4) hold one row's j-partials ----
    #pragma unroll
    for (int m = 1; m <= 8; m <<= 1) {
        #pragma unroll
        for (int sl = 0; sl < 8; ++sl) {
            Zp[sl] += __shfl_xor(Zp[sl], m, 64);
            Wp[sl] += __shfl_xor(Wp[sl], m, 64);
            Mp[sl] = fmaxf(Mp[sl], __shfl_xor(Mp[sl], m, 64));
        }
    }

    if (l15 == 0) {
        const float fx = intri[b * 18];                       // intri[b,0,0,0]
        const float dx = extri[b * 32 + 3]  - extri[b * 32 + 19];
        const float dy = extri[b * 32 + 7]  - extri[b * 32 + 23];
        const float dz = extri[b * 32 + 11] - extri[b * 32 + 27];
        const float bl = sqrtf(dx * dx + dy * dy + dz * dz);
        const float lfar = farp[b * 2];                       // far[b,0]
        const float kd = fx * bl / lfar;
        #pragma unroll
        for (int sl = 0; sl < 8; ++sl) {
            const int fi = sl >> 2, r = sl & 3;
            const int irow = rowbase + fi * 16 + l4 * 4 + r;
            const float Z = Zp[sl];
            const float conf = Mp[sl] / Z;
            const float corr = Wp[sl] / Z;
            float disp = fabsf(corr - (float)irow) * (1.0f / 512.0f);
            disp = fmaxf(disp, 0.1f);
            out[(size_t)(b * 2 + 0) * CH_STRIDE + h * W_DIM + irow] = kd / disp;
            out[(size_t)(b * 2 + 1) * CH_STRIDE + h * W_DIM + irow] = conf;
        }
    }
#undef ISSUE
#undef STAGE
#undef COMPUTE
}

extern "C" void kernel_launch(void* const* d_in, const int* in_sizes, int n_in,
                              void* d_out, int out_size, void* d_ws, size_t ws_size,
                              hipStream_t stream) {
    const float* feat  = (const float*)d_in[0];
    const float* extri = (const float*)d_in[1];
    const float* intri = (const float*)d_in[2];
    const float* farp  = (const float*)d_in[4];   // d_in[3] = near (unused)
    float* out = (float*)d_out;
    costvol_kernel<<<dim3(1024), dim3(512), 0, stream>>>(feat, extri, intri, farp, out);
}